// Round 2
// 282.552 us; speedup vs baseline: 1.0412x; 1.0412x over previous
//
#include <hip/hip_runtime.h>

typedef short s16x8 __attribute__((ext_vector_type(8)));  // 8 bf16 (guide-verified spelling)
typedef float f32x4 __attribute__((ext_vector_type(4)));

#define CODES_ELEMS 8388608   // 16*1024*512
#define N_ROWS      131072    // 16*1024*8
#define IDX_OFF     CODES_ELEMS
#define LOSS_OFF    (CODES_ELEMS + N_ROWS)

// d_ws: [0,4) loss acc; [4,8) flagged count; [64,8256) cc[2048];
// [8448,532736) cbs bf16-split tiled codebook [chunk16][seg4][ct8][lane64][8];
// [532736,...) flagged-row list
#define WS_LOSS 0
#define WS_CNT  4
#define WS_CC   64
#define WS_CBS  8448
#define WS_LIST 532736
// 0.05 validated r11 exact-tracked; packed-min truncation adds <2*0.004 ->
// 0.0625 keeps "unflagged => exact-gap >= 0.054 >= 0.05" (r9/r10 validated 0.25)
#define MARGIN_T 0.0625f

__device__ __forceinline__ float bf2f(unsigned short h) { return __uint_as_float(((unsigned)h) << 16); }
__device__ __forceinline__ unsigned short f2bf(float f) {   // RNE
  unsigned u = __float_as_uint(f);
  u += 0x7fffu + ((u >> 16) & 1u);
  return (unsigned short)(u >> 16);
}
// async global->LDS, 16B/lane; dest = wave-uniform base + lane*16
__device__ __forceinline__ void gl_lds16(const void* g, void* l) {
  __builtin_amdgcn_global_load_lds(
      (__attribute__((address_space(1))) void*)(g),
      (__attribute__((address_space(3))) void*)(l), 16, 0, 0);
}

// Fused prep (was prep1+prep2): bf16 split of codebook into MFMA-B tiled
// layout AND cc[k]=sum_d c^2. Each 64-lane wave holds exactly one code's
// 64 dims (d = lane) -> same butterfly order as validated prep1 (bit-identical
// cc; both waves of a code write the same value). Zeroes loss/cnt.
__global__ __launch_bounds__(256) void vq_prep(const float* __restrict__ cb,
                                               float* __restrict__ cc,
                                               unsigned short* __restrict__ cbs,
                                               float* __restrict__ loss,
                                               int* __restrict__ cnt) {
  int t = threadIdx.x;
  if (blockIdx.x == 0 && t == 0) { loss[0] = 0.f; cnt[0] = 0; }
  int e = blockIdx.x * 256 + t;   // 1024*256 = 2048 codes * 128 K-elems
  int k = e >> 7, K = e & 127;
  int s = K >> 5, rem = K & 31, q = rem >> 3, j = rem & 7;
  int d = (s < 2) ? K : (K - 64);
  float c = cb[k * 64 + d];
  unsigned short c1 = f2bf(c);
  unsigned short val = (s < 2) ? c1 : f2bf(c - bf2f(c1));  // exact residual split
  int chunk = k >> 7, ct = (k >> 4) & 7, n = k & 15;
  cbs[(((chunk * 4 + s) * 8 + ct) * 64 + (q * 16 + n)) * 8 + j] = val;
  // per-wave: d = lane (w0/w2: limb1 segs, w1/w3: residual segs — same |c|)
  float sq = c * c;
  #pragma unroll
  for (int m = 1; m < 64; m <<= 1) sq += __shfl_xor(sq, m, 64);
  if ((t & 63) == 0) cc[k] = sq;
}

// Main (r11 math, restructured): block = 256 rows x 2048 codes, 4 waves,
// FOUR 16-row tiles per wave (each B-fragment read feeds 4 MFMA groups).
// Segs 4/5 (duplicate c1) removed: az2 products reuse b0/b1 registers.
// Double-buffered global_load_lds staging: chunk+1 issued before computing
// chunk; the single per-chunk __syncthreads drains an already-landed prefetch.
// Argmin/second tracked as packed u32 (trunc-dist | pid) — acc init = cc+zz
// makes all distances positive (min true dist ~60 for this data) so uint-min
// == float-min; pid=chunk*8+ct keeps ascending-code first-wins within a lane.
__global__ __launch_bounds__(256) void VQQuantizer_30064771072206_kernel(
    const float* __restrict__ zf, const unsigned short* __restrict__ cbs,
    const float* __restrict__ cc, int* __restrict__ cnt, int* __restrict__ list,
    float* __restrict__ out)
{
  __shared__ __align__(16) unsigned short bt[2][16384];  // 2 x 32 KB: [seg4][ct8][lane64][8]
  __shared__ __align__(16) float cc_l[2048];             // full cc, loaded once
  const int t = threadIdx.x, w = t >> 6, l = t & 63;
  const int col = l & 15, q = l >> 4;
  const int R0 = blockIdx.x * 256;
  const float4* zf4 = (const float4*)zf;

  // prologue stage: chunk 0 -> buf 0 (issued first so latency hides under setup)
  #pragma unroll
  for (int i = 0; i < 8; ++i) {
    int unit = i * 4 + w;            // wave-uniform: seg=unit>>3, ct=unit&7
    gl_lds16(cbs + (size_t)(unit * 64 + l) * 8, &bt[0][unit * 512]);
  }
  #pragma unroll
  for (int i = 0; i < 2; ++i) {
    int idx = i * 256 + t;
    ((float4*)cc_l)[idx] = ((const float4*)cc)[idx];
  }

  // A-fragments per tile: lane holds A[m=l&15][k=q*8+j]; plus per-row zz
  // (zz is row-constant: shifts all candidates of a row equally -> gaps and
  // argmin unchanged; makes dist ~= true ||z-c||^2 >= ~60 > 0 for uint-min).
  s16x8 az1[4][2], az2[4][2];   // [tile][seg]
  float zzr[4][4];              // [tile][r]: zz of row q*4+r (C/D row layout)
  #pragma unroll
  for (int tile = 0; tile < 4; ++tile) {
    int row = R0 + tile * 64 + 16 * w + col;
    const float4* zr = zf4 + (size_t)row * 16;
    float zzp = 0.f;
    #pragma unroll
    for (int s = 0; s < 2; ++s) {
      float4 u0 = zr[s * 8 + q * 2];
      float4 u1 = zr[s * 8 + q * 2 + 1];
      zzp += u0.x*u0.x + u0.y*u0.y + u0.z*u0.z + u0.w*u0.w;
      zzp += u1.x*u1.x + u1.y*u1.y + u1.z*u1.z + u1.w*u1.w;
      float m2[8] = {-2.f*u0.x, -2.f*u0.y, -2.f*u0.z, -2.f*u0.w,
                     -2.f*u1.x, -2.f*u1.y, -2.f*u1.z, -2.f*u1.w};
      #pragma unroll
      for (int j = 0; j < 8; ++j) {
        unsigned short h1 = f2bf(m2[j]);
        unsigned short h2 = f2bf(m2[j] - bf2f(h1));
        az1[tile][s][j] = (short)h1;
        az2[tile][s][j] = (short)h2;
      }
    }
    zzp += __shfl_xor(zzp, 16, 64);   // sum over the 4 q-groups -> zz[row(col)]
    zzp += __shfl_xor(zzp, 32, 64);
    #pragma unroll
    for (int r = 0; r < 4; ++r)
      zzr[tile][r] = __shfl(zzp, q * 4 + r, 64);   // zz for this lane's acc rows
  }

  unsigned p1[4][4], p2[4][4];   // packed (trunc dist | pid): best / second
  #pragma unroll
  for (int tile = 0; tile < 4; ++tile)
    #pragma unroll
    for (int r = 0; r < 4; ++r) { p1[tile][r] = 0xFFFFFFFFu; p2[tile][r] = 0xFFFFFFFFu; }

  __syncthreads();   // drains prologue stage (vmcnt 0) + cc_l writes

  int cur = 0;
  for (int chunk = 0; chunk < 16; ++chunk) {
    if (chunk + 1 < 16) {            // issue next-chunk stage into buf^1
      const unsigned short* src = cbs + (size_t)(chunk + 1) * 16384;
      unsigned short* dst = &bt[cur ^ 1][0];
      #pragma unroll
      for (int i = 0; i < 8; ++i) {
        int unit = i * 4 + w;
        gl_lds16(src + (size_t)(unit * 64 + l) * 8, dst + unit * 512);
      }
    }
    const unsigned short* bb = &bt[cur][l * 8];
    const float* ccc = &cc_l[chunk * 128 + col];
    #pragma unroll
    for (int ct = 0; ct < 8; ++ct) {
      float nh = ccc[ct * 16];
      const unsigned short* base = bb + ct * 512;
      s16x8 b0 = *(const s16x8*)(base);             // c1 dims 0-31
      s16x8 b1 = *(const s16x8*)(base + 4096);      // c1 dims 32-63
      s16x8 b2 = *(const s16x8*)(base + 8192);      // c-resid dims 0-31
      s16x8 b3 = *(const s16x8*)(base + 12288);     // c-resid dims 32-63
      unsigned pid = (unsigned)(chunk * 8 + ct);    // 7 bits, ascending = code order
      #pragma unroll
      for (int tile = 0; tile < 4; ++tile) {
        f32x4 acc;
        acc[0] = nh + zzr[tile][0];
        acc[1] = nh + zzr[tile][1];
        acc[2] = nh + zzr[tile][2];
        acc[3] = nh + zzr[tile][3];
        acc = __builtin_amdgcn_mfma_f32_16x16x32_bf16(az1[tile][0], b0, acc, 0, 0, 0);
        acc = __builtin_amdgcn_mfma_f32_16x16x32_bf16(az1[tile][1], b1, acc, 0, 0, 0);
        acc = __builtin_amdgcn_mfma_f32_16x16x32_bf16(az1[tile][0], b2, acc, 0, 0, 0);
        acc = __builtin_amdgcn_mfma_f32_16x16x32_bf16(az1[tile][1], b3, acc, 0, 0, 0);
        acc = __builtin_amdgcn_mfma_f32_16x16x32_bf16(az2[tile][0], b0, acc, 0, 0, 0);  // reuse b0
        acc = __builtin_amdgcn_mfma_f32_16x16x32_bf16(az2[tile][1], b1, acc, 0, 0, 0);  // reuse b1
        #pragma unroll
        for (int r = 0; r < 4; ++r) {   // packed (best, second) update: 4 int ops
          unsigned pd = (__float_as_uint(acc[r]) & 0xFFFFFF80u) | pid;
          unsigned mx = p1[tile][r] > pd ? p1[tile][r] : pd;
          p2[tile][r] = p2[tile][r] < mx ? p2[tile][r] : mx;
          p1[tile][r] = p1[tile][r] < pd ? p1[tile][r] : pd;
        }
      }
    }
    __syncthreads();   // all readers done with cur; prefetch into cur^1 landed
    cur ^= 1;
  }

  // unpack, then merge (best, idx, second) across the 16 lanes of each row group
  #pragma unroll
  for (int tile = 0; tile < 4; ++tile) {
    #pragma unroll
    for (int r = 0; r < 4; ++r) {
      float a   = __uint_as_float(p1[tile][r] & 0xFFFFFF80u);
      int   ia  = (int)(p1[tile][r] & 127u) * 16 + col;   // code = pid*16 + col
      float b2v = __uint_as_float(p2[tile][r] & 0xFFFFFF80u);
      #pragma unroll
      for (int m = 1; m < 16; m <<= 1) {
        float oa = __shfl_xor(a, m, 64);
        int   oi = __shfl_xor(ia, m, 64);
        float ob = __shfl_xor(b2v, m, 64);
        float hi = fmaxf(a, oa);
        b2v = fminf(fminf(b2v, ob), hi);
        bool take = (oa < a) || (oa == a && oi < ia);
        a = take ? oa : a; ia = take ? oi : ia;
      }
      if (col == 0) {   // C/D: col=l&15, row=(l>>4)*4+r [m89, validated r9-r11]
        int row = R0 + tile * 64 + 16 * w + q * 4 + r;
        out[IDX_OFF + row] = (float)ia;
        if (b2v - a < MARGIN_T) {
          int p = atomicAdd(cnt, 1);
          list[p] = row;
        }
      }
    }
  }
}

// Rescore v3 (unchanged, validated r10/r11): 8 flagged rows per block share one
// exact fp32 codebook sweep; per (row,code) chain identical to reference order.
__global__ __launch_bounds__(256) void vq_rescore(
    const float* __restrict__ zf, const float* __restrict__ cb,
    const float* __restrict__ cc, const int* __restrict__ cnt,
    const int* __restrict__ list, float* __restrict__ out)
{
  __shared__ __align__(16) float zl[8][68];
  __shared__ float zz_l[8];
  __shared__ int   rows_s[8];
  __shared__ float rv[4][8];
  __shared__ int   ri[4][8];
  const int t = threadIdx.x, w = t >> 6, l = t & 63;
  const int count = cnt[0];
  const float4* cb4 = (const float4*)cb;

  for (int itb = blockIdx.x; itb * 8 < count; itb += 1024) {
    if (itb != (int)blockIdx.x) __syncthreads();
    if (t < 8) {
      int ii = itb * 8 + t;
      rows_s[t] = list[ii < count ? ii : count - 1];  // tail dup: benign rewrite
    }
    __syncthreads();
    if (t < 128) {
      int r = t >> 4, dq = t & 15;
      *(float4*)&zl[r][dq * 4] = ((const float4*)zf)[(size_t)rows_s[r] * 16 + dq];
    }
    __syncthreads();
    if (t < 8) {                          // zz: sequential-d np chain
      float s = 0.f;
      for (int d = 0; d < 64; ++d) { float v = zl[t][d]; s += v * v; }
      zz_l[t] = s;
    }
    __syncthreads();

    float bv[8]; int bi[8];
    #pragma unroll
    for (int r = 0; r < 8; ++r) { bv[r] = 3.402823466e38f; bi[r] = 0; }
    #pragma unroll 1
    for (int o = 0; o < 8; ++o) {         // thread's codes ascending: o*256+t
      int c = o * 256 + t;
      const float4* cr = cb4 + (size_t)c * 16;
      float a[8];
      #pragma unroll
      for (int r = 0; r < 8; ++r) a[r] = 0.f;
      #pragma unroll
      for (int dq = 0; dq < 16; ++dq) {
        float4 cv = cr[dq];
        #pragma unroll
        for (int r = 0; r < 8; ++r) {
          float4 z4 = *(const float4*)&zl[r][dq * 4];   // broadcast (free)
          a[r] += z4.x * cv.x;
          a[r] += z4.y * cv.y;
          a[r] += z4.z * cv.z;
          a[r] += z4.w * cv.w;
        }
      }
      float ccv = cc[c];
      #pragma unroll
      for (int r = 0; r < 8; ++r) {
        float t0 = zz_l[r] - 2.0f * a[r];
        float dist = t0 + ccv;
        if (dist < bv[r]) { bv[r] = dist; bi[r] = c; }
      }
    }
    #pragma unroll
    for (int r = 0; r < 8; ++r) {
      float v = bv[r]; int idx = bi[r];
      #pragma unroll
      for (int m = 1; m < 64; m <<= 1) {
        float ov = __shfl_xor(v, m, 64); int oi = __shfl_xor(idx, m, 64);
        if (ov < v || (ov == v && oi < idx)) { v = ov; idx = oi; }
      }
      if (l == 0) { rv[w][r] = v; ri[w][r] = idx; }
    }
    __syncthreads();
    if (t < 8) {
      float fv = rv[0][t]; int fi = ri[0][t];
      #pragma unroll
      for (int k = 1; k < 4; ++k) {
        if (rv[k][t] < fv || (rv[k][t] == fv && ri[k][t] < fi)) { fv = rv[k][t]; fi = ri[k][t]; }
      }
      out[IDX_OFF + rows_s[t]] = (float)fi;
    }
  }
}

// codes = zg + (zq - zg), commit loss fp32 (validated epilogue, idx from out).
__global__ __launch_bounds__(256) void vq_epilogue(
    const float* __restrict__ zf, const float* __restrict__ cb,
    float* __restrict__ loss, float* __restrict__ out)
{
  __shared__ int idxb[64];
  __shared__ float wsum[4];
  int t = threadIdx.x;
  int R0 = blockIdx.x * 64;
  if (t < 64) idxb[t] = (int)out[IDX_OFF + R0 + t];
  __syncthreads();
  const float4* zf4 = (const float4*)zf;
  const float4* cb4 = (const float4*)cb;
  float4* out4 = (float4*)out;
  float lsum = 0.f;
  #pragma unroll
  for (int i = 0; i < 4; ++i) {
    int f = i * 256 + t;
    int row = f >> 4, dq = f & 15;
    int k = idxb[row];
    float4 qv = cb4[(size_t)k * 16 + dq];
    float4 zv = zf4[(size_t)(R0 + row) * 16 + dq];
    float dx = qv.x - zv.x, dy = qv.y - zv.y, dz = qv.z - zv.z, dw = qv.w - zv.w;
    float4 st; st.x = zv.x + dx; st.y = zv.y + dy; st.z = zv.z + dz; st.w = zv.w + dw;
    out4[(size_t)(R0 + row) * 16 + dq] = st;
    lsum += dx * dx; lsum += dy * dy; lsum += dz * dz; lsum += dw * dw;
  }
  #pragma unroll
  for (int m = 1; m < 64; m <<= 1) lsum += __shfl_xor(lsum, m, 64);
  if ((t & 63) == 0) wsum[t >> 6] = lsum;
  __syncthreads();
  if (t == 0) atomicAdd(loss, wsum[0] + wsum[1] + wsum[2] + wsum[3]);
}

__global__ void vq_finalize(const float* __restrict__ loss, float* __restrict__ out) {
  out[LOSS_OFF] = loss[0] * (1.f / 8388608.f);
}

extern "C" void kernel_launch(void* const* d_in, const int* in_sizes, int n_in,
                              void* d_out, int out_size, void* d_ws, size_t ws_size,
                              hipStream_t stream) {
  const float* z  = (const float*)d_in[0];
  const float* cb = (const float*)d_in[1];
  float* out = (float*)d_out;
  float* loss = (float*)((char*)d_ws + WS_LOSS);
  int*   cnt  = (int*)((char*)d_ws + WS_CNT);
  float* cc   = (float*)((char*)d_ws + WS_CC);
  unsigned short* cbs = (unsigned short*)((char*)d_ws + WS_CBS);
  int*   list = (int*)((char*)d_ws + WS_LIST);

  vq_prep<<<1024, 256, 0, stream>>>(cb, cc, cbs, loss, cnt);
  VQQuantizer_30064771072206_kernel<<<512, 256, 0, stream>>>(z, cbs, cc, cnt, list, out);
  vq_rescore<<<1024, 256, 0, stream>>>(z, cb, cc, cnt, list, out);
  vq_epilogue<<<2048, 256, 0, stream>>>(z, cb, loss, out);
  vq_finalize<<<1, 1, 0, stream>>>(loss, out);
}